// Round 8
// baseline (103.655 us; speedup 1.0000x reference)
//
#include <hip/hip_runtime.h>

// DILATE loss: 0.5*soft-DTW(value) + 0.5*<softDTW-grad, Omega>.
// B=64, T=128, C=4 -> M=256 independent sequences, N=128, gamma=0.01.
//
// Fused forward pass carrying (R', Rdot): R' = -K2*R (log2-scaled), Rdot =
// JVP of soft-DTW value in direction Omega == sum(E*Omega). Math identical
// to R7 (absmax 0.0 verified).
//
// R8 change: occupancy packing. 256 one-wave blocks spread over 256 CUs left
// 3/4 SIMDs idle and the busy SIMD with a single wave that cannot fill its
// own dependency/cadence stalls (R7 showed issue-count changes are neutral ->
// stall-bound). Now: block = 512 threads = 8 waves = 8 sequences, grid = 32.
// The 8 waves are co-resident on ONE CU -> 2 waves/SIMD share issue, so one
// wave's stall cycles run the sibling wave's independent sequence (m114:
// co-resident waves overlap ~perfectly). Each wave uses a private 384-float
// LDS slice -> zero barriers; per-wave code unchanged.

#define TN 128
#define BATCH 64
#define CH 4

__device__ __forceinline__ float fast_exp2(float x) { return __builtin_amdgcn_exp2f(x); }
__device__ __forceinline__ float fast_log2(float x) { return __builtin_amdgcn_logf(x); }
__device__ __forceinline__ float fast_rcp(float x)  { return __builtin_amdgcn_rcpf(x); }

// lane i <- lane i-1, lane 0 <- fill   (DPP wave_shr:1) — HW-verified R4-R7
__device__ __forceinline__ float dpp_shr1(float x, float fill) {
  union { float f; int i; } o, s, r;
  o.f = fill; s.f = x;
  r.i = __builtin_amdgcn_update_dpp(o.i, s.i, 0x138, 0xF, 0xF, false);
  return r.f;
}

__global__ __launch_bounds__(512)
void dilate_softdtw_kernel(const float* __restrict__ outputs,
                           const float* __restrict__ targets,
                           float* __restrict__ out) {
  // per-wave private padded o: slice of 384 floats; oc[k]=o[k] for k in [0,128).
  __shared__ float obuf[8 * 384];

  const float WALLP = -4.328085e6f;  // -K2*30000: boundary wall, scaled units
  const float O_PAD = 15.0f;         // sentinel: (t-15)^2 ~ 100..400 per OOB step
  const float K2    = 144.2695040888963f;     // (1/gamma)*log2(e)

  const int wid  = threadIdx.x >> 6;        // wave 0..7
  const int lane = threadIdx.x & 63;        // 0..63
  const int m = blockIdx.x * 8 + wid;       // sequence 0..255
  const int b = m >> 2, c = m & 3;
  const int i0 = 2*lane + 1;                // rows i0, i1=i0+1

  const float* tb = targets + (size_t)b*(TN*CH) + c;
  const float* ob = outputs + (size_t)b*(TN*CH) + c;

  float* slice = obuf + wid * 384;
  #pragma unroll
  for (int s = 0; s < 6; ++s) {
    const int idx = lane + 64*s;
    const int k = idx - 126;
    slice[idx] = ((unsigned)k <= 127u) ? ob[k*CH] : O_PAD;
  }
  const float t0 = tb[(i0 - 1)*CH];   // t[i0]
  const float t1 = tb[i0*CH];         // t[i1]
  // no barrier: LDS slice is wave-private; compiler orders ds_write->ds_read.

  const float* oc = slice + 126;

  // ---- peel d=2: R'(1,1) = -K2*D(1,1); Rdot(1,1) = Omega(1,1) = 0 ----
  float p1_0, p1_1 = WALLP, p2_0 = WALLP, up2 = WALLP;       // R' diagonals
  float dp1_0 = 0.f, dp1_1 = 0.f, dp2_0 = 0.f, dup2 = 0.f;   // Rdot diagonals
  {
    float df = t0 - oc[0];
    p1_0 = (lane == 0) ? -K2*df*df : WALLP;
  }
  float fd0 = (float)(2*i0 - 3);  // i0 - j0 at d=3
  float fd1 = fd0 + 2.0f;         // i1 - j1
  float o0 = oc[2 - i0];          // o[j0-1] at d=3
  float o1 = oc[1 - i0];          // o[j0-2] at d=3

  #pragma unroll 2
  for (int d = 3; d <= 2*TN; ++d) {
    const int j0 = d - i0;
    const float o_nxt = oc[j0];          // prefetch next iter's o[j0-1]
    float up1  = dpp_shr1(p1_1, WALLP);  // R'[i0-1][j0]    (row 0 -> wall)
    float dup1 = dpp_shr1(dp1_1, 0.f);   // Rdot[i0-1][j0]  (weight 0 anyway)

    // --- exp args, both cells ---
    float mn1 = fmaxf(p2_0, fmaxf(p1_0, p1_1));   // cell (i1, j0-1)
    float mn0 = fmaxf(up2,  fmaxf(up1,  p1_0));   // cell (i0, j0)
    float a1 = p2_0 - mn1, b1 = p1_0 - mn1, c1 = p1_1 - mn1;
    float a0 = up2  - mn0, b0 = up1  - mn0, c0 = p1_0 - mn0;

    float ea1 = fast_exp2(a1);
    float eb1 = fast_exp2(b1);
    float ec1 = fast_exp2(c1);
    float ea0 = fast_exp2(a0);
    float eb0 = fast_exp2(b0);
    float ec0 = fast_exp2(c0);

    float sum1 = (ea1 + eb1) + ec1;
    float sum0 = (ea0 + eb0) + ec0;
    float rs1 = fast_rcp(sum1);
    float rs0 = fast_rcp(sum0);
    float l1  = fast_log2(sum1);
    float l0  = fast_log2(sum0);

    float df1 = t1 - o1, df0 = t0 - o0;
    float q1 = df1*df1,  q0 = df0*df0;
    float jv1 = __builtin_fmaf(ea1, dp2_0, __builtin_fmaf(eb1, dp1_0, ec1*dp1_1));
    float jv0 = __builtin_fmaf(ea0, dup2,  __builtin_fmaf(eb0, dup1,  ec0*dp1_0));
    float w1 = fd1*fd1, w0 = fd0*fd0;

    float c1v = __builtin_fmaf(-K2, q1, mn1 + l1);
    float c0v = __builtin_fmaf(-K2, q0, mn0 + l0);
    float d1v = __builtin_fmaf(rs1, jv1, w1);
    float d0v = __builtin_fmaf(rs0, jv0, w0);

    // rotate register pipelines
    p2_0 = p1_0;   p1_0 = c0v;  p1_1 = c1v;  up2 = up1;
    dp2_0 = dp1_0; dp1_0 = d0v; dp1_1 = d1v; dup2 = dup1;
    o1 = o0; o0 = o_nxt;
    fd0 -= 1.0f; fd1 -= 1.0f;
  }

  // lane 63 holds cell (128,128): R = -gamma*ln2 * R', Rdot = sum(E*Omega).
  if (lane == 63) {
    // 0.5*R/B + 0.5*Rdot/(B*T*T);  0.5*(gamma*ln2)/64 = 5.4152123e-5
    const float partial = __builtin_fmaf(p1_1, -5.415212348e-5f,
                                         dp1_1 * 4.76837158203125e-7f);
    atomicAdd(out, partial);
  }
}

extern "C" void kernel_launch(void* const* d_in, const int* in_sizes, int n_in,
                              void* d_out, int out_size, void* d_ws, size_t ws_size,
                              hipStream_t stream) {
  const float* outputs = (const float*)d_in[0];   // [64,128,4]
  const float* targets = (const float*)d_in[1];   // [64,128,4]
  float* out = (float*)d_out;                     // scalar fp32
  (void)in_sizes; (void)n_in; (void)out_size; (void)d_ws; (void)ws_size;

  // d_out is poisoned to 0xAA before every timed launch — zero it ourselves.
  (void)hipMemsetAsync(out, 0, sizeof(float), stream);
  // 32 blocks x 512 threads: 8 waves/block co-resident on one CU = 2 waves/SIMD.
  dilate_softdtw_kernel<<<dim3(32), dim3(512), 0, stream>>>(outputs, targets, out);
}

// Round 9
// 88.244 us; speedup vs baseline: 1.1746x; 1.1746x over previous
//
#include <hip/hip_runtime.h>

// DILATE loss: 0.5*soft-DTW(value) + 0.5*<softDTW-grad, Omega>.
// B=64, T=128, C=4 -> M=256 independent sequences, N=128, gamma=0.01.
//
// Fused forward pass carrying (R', Rdot): R' = -K2*R (log2-scaled), Rdot =
// JVP of soft-DTW value in direction Omega == sum(E*Omega). Math identical
// to R7 (absmax 0.0 verified). 256 blocks x 1 wave (R7 config - fastest).
//
// R9 change: ZERO LDS operations in the 254-step loop. R8's counters showed
// 2 waves/SIMD fill stalls to 79% busy while a lone wave sits ~60% -> ~120
// cyc/iter unfilled stall ~= one exposed ds_read. The per-lane o-stream
// o[d-2l-2] advances by exactly one lane per step, so it's implemented as a
// register pipeline: oA/oB shifted up-lane via DPP wave_shr:1, new values
// injected at lane 0 from a feeder register (lane0 = o[d]) that shifts
// down-lane via DPP wave_shl:1, reloaded from 2 preloaded window registers
// (o[3..66], o[67..130]) then constant O_PAD for d>=131.

#define TN 128
#define BATCH 64
#define CH 4

__device__ __forceinline__ float fast_exp2(float x) { return __builtin_amdgcn_exp2f(x); }
__device__ __forceinline__ float fast_log2(float x) { return __builtin_amdgcn_logf(x); }
__device__ __forceinline__ float fast_rcp(float x)  { return __builtin_amdgcn_rcpf(x); }

// lane i <- lane i-1, lane 0 <- old(fill)   (DPP wave_shr:1) — HW-verified R4-R8
__device__ __forceinline__ float dpp_shr1(float x, float fill) {
  union { float f; int i; } o, s, r;
  o.f = fill; s.f = x;
  r.i = __builtin_amdgcn_update_dpp(o.i, s.i, 0x138, 0xF, 0xF, false);
  return r.f;
}
// lane i <- lane i+1, lane 63 <- old(fill)  (DPP wave_shl:1) — HW-verified R4
__device__ __forceinline__ float dpp_shl1(float x, float fill) {
  union { float f; int i; } o, s, r;
  o.f = fill; s.f = x;
  r.i = __builtin_amdgcn_update_dpp(o.i, s.i, 0x130, 0xF, 0xF, false);
  return r.f;
}

__global__ __launch_bounds__(64)
void dilate_softdtw_kernel(const float* __restrict__ outputs,
                           const float* __restrict__ targets,
                           float* __restrict__ out) {
  // padded o staging (init only): oc[k]=o[k] for k in [0,128), pads = O_PAD.
  __shared__ float obuf[384];

  const float WALLP = -4.328085e6f;  // -K2*30000: boundary wall, scaled units
  const float O_PAD = 15.0f;         // sentinel: (t-15)^2 ~ 100..400 per OOB step
  const float K2    = 144.2695040888963f;     // (1/gamma)*log2(e)

  const int m = blockIdx.x, b = m >> 2, c = m & 3;
  const int lane = threadIdx.x;   // 0..63
  const int i0 = 2*lane + 1;      // rows i0, i1=i0+1

  const float* tb = targets + (size_t)b*(TN*CH) + c;
  const float* ob = outputs + (size_t)b*(TN*CH) + c;

  #pragma unroll
  for (int s = 0; s < 6; ++s) {
    const int idx = lane + 64*s;
    const int k = idx - 126;
    obuf[idx] = ((unsigned)k <= 127u) ? ob[k*CH] : O_PAD;
  }
  const float t0 = tb[(i0 - 1)*CH];   // t[i0]
  const float t1 = tb[i0*CH];         // t[i1]
  __syncthreads();

  const float* oc = obuf + 126;

  // ---- o register pipeline, state at start of d=3 ----
  // oA(l) = o[d-2l-2] (this step's o0), oB(l) = o[d-2l-1] (next step's o0),
  // o1(l) = o[d-2l-3]. Injection: oB'(0) = o[d] from oFeed lane 0.
  float oA = oc[1 - 2*lane];
  float oB = oc[2 - 2*lane];
  float o1 = oc[0 - 2*lane];
  float oF0 = oc[lane + 3];     // feeder window: o[3..66]
  float oF1 = oc[lane + 67];    // feeder window: o[67..130] (>=128 are pads)
  const float oPadv = O_PAD;

  // ---- peel d=2: R'(1,1) = -K2*D(1,1); Rdot(1,1) = Omega(1,1) = 0 ----
  float p1_0, p1_1 = WALLP, p2_0 = WALLP, up2 = WALLP;       // R' diagonals
  float dp1_0 = 0.f, dp1_1 = 0.f, dp2_0 = 0.f, dup2 = 0.f;   // Rdot diagonals
  {
    float df = t0 - oc[0];
    p1_0 = (lane == 0) ? -K2*df*df : WALLP;
  }
  float fd0 = (float)(2*i0 - 3);  // i0 - j0 at d=3
  float fd1 = fd0 + 2.0f;         // i1 - j1
  float oFeed;

  auto step = [&]() {
    float up1  = dpp_shr1(p1_1, WALLP);  // R'[i0-1][j0]    (row 0 -> wall)
    float dup1 = dpp_shr1(dp1_1, 0.f);   // Rdot[i0-1][j0]  (weight 0 anyway)

    // o pipeline advance (independent of the value chain)
    float oBn = dpp_shr1(oA, oFeed);     // lane0 <- o[d]
    oFeed = dpp_shl1(oFeed, oPadv);

    // --- exp args, both cells ---
    float mn1 = fmaxf(p2_0, fmaxf(p1_0, p1_1));   // cell (i1, j0-1)
    float mn0 = fmaxf(up2,  fmaxf(up1,  p1_0));   // cell (i0, j0)
    float a1 = p2_0 - mn1, b1 = p1_0 - mn1, c1 = p1_1 - mn1;
    float a0 = up2  - mn0, b0 = up1  - mn0, c0 = p1_0 - mn0;

    float ea1 = fast_exp2(a1);
    float eb1 = fast_exp2(b1);
    float ec1 = fast_exp2(c1);
    float ea0 = fast_exp2(a0);
    float eb0 = fast_exp2(b0);
    float ec0 = fast_exp2(c0);

    float sum1 = (ea1 + eb1) + ec1;
    float sum0 = (ea0 + eb0) + ec0;
    float rs1 = fast_rcp(sum1);
    float rs0 = fast_rcp(sum0);
    float l1  = fast_log2(sum1);
    float l0  = fast_log2(sum0);

    float df1 = t1 - o1, df0 = t0 - oA;
    float q1 = df1*df1,  q0 = df0*df0;
    float jv1 = __builtin_fmaf(ea1, dp2_0, __builtin_fmaf(eb1, dp1_0, ec1*dp1_1));
    float jv0 = __builtin_fmaf(ea0, dup2,  __builtin_fmaf(eb0, dup1,  ec0*dp1_0));
    float w1 = fd1*fd1, w0 = fd0*fd0;

    float c1v = __builtin_fmaf(-K2, q1, mn1 + l1);
    float c0v = __builtin_fmaf(-K2, q0, mn0 + l0);
    float d1v = __builtin_fmaf(rs1, jv1, w1);
    float d0v = __builtin_fmaf(rs0, jv0, w0);

    // rotate register pipelines
    p2_0 = p1_0;   p1_0 = c0v;  p1_1 = c1v;  up2 = up1;
    dp2_0 = dp1_0; dp1_0 = d0v; dp1_1 = d1v; dup2 = dup1;
    o1 = oA; oA = oB; oB = oBn;
    fd0 -= 1.0f; fd1 -= 1.0f;
  };

  // d = 3..66, 67..130, 131..256  (254 steps total)
  oFeed = oF0;
  #pragma unroll 2
  for (int k = 0; k < 64; ++k) step();
  oFeed = oF1;
  #pragma unroll 2
  for (int k = 0; k < 64; ++k) step();
  oFeed = oPadv;
  #pragma unroll 2
  for (int k = 0; k < 126; ++k) step();

  // lane 63 holds cell (128,128): R = -gamma*ln2 * R', Rdot = sum(E*Omega).
  if (lane == 63) {
    // 0.5*R/B + 0.5*Rdot/(B*T*T);  0.5*(gamma*ln2)/64 = 5.4152123e-5
    const float partial = __builtin_fmaf(p1_1, -5.415212348e-5f,
                                         dp1_1 * 4.76837158203125e-7f);
    atomicAdd(out, partial);
  }
}

extern "C" void kernel_launch(void* const* d_in, const int* in_sizes, int n_in,
                              void* d_out, int out_size, void* d_ws, size_t ws_size,
                              hipStream_t stream) {
  const float* outputs = (const float*)d_in[0];   // [64,128,4]
  const float* targets = (const float*)d_in[1];   // [64,128,4]
  float* out = (float*)d_out;                     // scalar fp32
  (void)in_sizes; (void)n_in; (void)out_size; (void)d_ws; (void)ws_size;

  // d_out is poisoned to 0xAA before every timed launch — zero it ourselves.
  (void)hipMemsetAsync(out, 0, sizeof(float), stream);
  // 256 blocks x 1 wave: all 256 CUs busy (R8 showed packing loses CUs).
  dilate_softdtw_kernel<<<dim3(256), dim3(64), 0, stream>>>(outputs, targets, out);
}

// Round 10
// 84.229 us; speedup vs baseline: 1.2306x; 1.0477x over previous
//
#include <hip/hip_runtime.h>

// DILATE loss: 0.5*soft-DTW(value) + 0.5*<softDTW-grad, Omega>.
// B=64, T=128, C=4 -> M=256 independent sequences, N=128, gamma=0.01.
//
// Fused forward pass carrying (R', Rdot): R' = -K2*R (log2-scaled), Rdot =
// JVP of soft-DTW value in direction Omega == sum(E*Omega). One block = one
// wave = one sequence (R8 proved packing loses: only 256 independent chains
// exist, and k-per-issue-stream costs k*230 > 318 cyc/iter). Per-wave math
// identical to R7 (absmax 0.0 verified).
//
// R10 change: #pragma unroll 4 (was 2). Model: wall 318 cyc/iter = issue
// ~230 (10 trans x ~16cyc + ~35 VALU x 2) + ~90 cyc dependency gaps around
// the log2->value->next-max3 chain. Deeper unroll gives the backend
// scheduler cross-iteration material (batched o prefetches, sibling-cell
// Rdot blocks) to fill those gaps. R9's register-pipeline o (H-LDS) is
// reverted: it added DPP issue on the chain (+19 cyc/iter).

#define TN 128
#define BATCH 64
#define CH 4

__device__ __forceinline__ float fast_exp2(float x) { return __builtin_amdgcn_exp2f(x); }
__device__ __forceinline__ float fast_log2(float x) { return __builtin_amdgcn_logf(x); }
__device__ __forceinline__ float fast_rcp(float x)  { return __builtin_amdgcn_rcpf(x); }

// lane i <- lane i-1, lane 0 <- old(fill)   (DPP wave_shr:1) — HW-verified R4-R9
__device__ __forceinline__ float dpp_shr1(float x, float fill) {
  union { float f; int i; } o, s, r;
  o.f = fill; s.f = x;
  r.i = __builtin_amdgcn_update_dpp(o.i, s.i, 0x138, 0xF, 0xF, false);
  return r.f;
}

__global__ __launch_bounds__(64)
void dilate_softdtw_kernel(const float* __restrict__ outputs,
                           const float* __restrict__ targets,
                           float* __restrict__ out) {
  // padded o: oc[k]=o[k] for k in [0,128); pads hold O_PAD sentinel.
  __shared__ float obuf[384];

  const float WALLP = -4.328085e6f;  // -K2*30000: boundary wall, scaled units
  const float O_PAD = 15.0f;         // sentinel: (t-15)^2 ~ 100..400 per OOB step
  const float K2    = 144.2695040888963f;     // (1/gamma)*log2(e)

  const int m = blockIdx.x, b = m >> 2, c = m & 3;
  const int lane = threadIdx.x;   // 0..63
  const int i0 = 2*lane + 1;      // rows i0, i1=i0+1

  const float* tb = targets + (size_t)b*(TN*CH) + c;
  const float* ob = outputs + (size_t)b*(TN*CH) + c;

  #pragma unroll
  for (int s = 0; s < 6; ++s) {
    const int idx = lane + 64*s;
    const int k = idx - 126;
    obuf[idx] = ((unsigned)k <= 127u) ? ob[k*CH] : O_PAD;
  }
  const float t0 = tb[(i0 - 1)*CH];   // t[i0]
  const float t1 = tb[i0*CH];         // t[i1]
  __syncthreads();

  const float* oc = obuf + 126;

  // ---- peel d=2: R'(1,1) = -K2*D(1,1); Rdot(1,1) = Omega(1,1) = 0 ----
  float p1_0, p1_1 = WALLP, p2_0 = WALLP, up2 = WALLP;       // R' diagonals
  float dp1_0 = 0.f, dp1_1 = 0.f, dp2_0 = 0.f, dup2 = 0.f;   // Rdot diagonals
  {
    float df = t0 - oc[0];
    p1_0 = (lane == 0) ? -K2*df*df : WALLP;
  }
  float fd0 = (float)(2*i0 - 3);  // i0 - j0 at d=3
  float fd1 = fd0 + 2.0f;         // i1 - j1
  float o0 = oc[2 - i0];          // o[j0-1] at d=3
  float o1 = oc[1 - i0];          // o[j0-2] at d=3

  #pragma unroll 4
  for (int d = 3; d <= 2*TN; ++d) {
    const int j0 = d - i0;
    const float o_nxt = oc[j0];          // prefetch next iter's o[j0-1]
    float up1  = dpp_shr1(p1_1, WALLP);  // R'[i0-1][j0]    (row 0 -> wall)
    float dup1 = dpp_shr1(dp1_1, 0.f);   // Rdot[i0-1][j0]  (weight 0 anyway)

    // --- exp args, both cells ---
    float mn1 = fmaxf(p2_0, fmaxf(p1_0, p1_1));   // cell (i1, j0-1)
    float mn0 = fmaxf(up2,  fmaxf(up1,  p1_0));   // cell (i0, j0)
    float a1 = p2_0 - mn1, b1 = p1_0 - mn1, c1 = p1_1 - mn1;
    float a0 = up2  - mn0, b0 = up1  - mn0, c0 = p1_0 - mn0;

    float ea1 = fast_exp2(a1);
    float eb1 = fast_exp2(b1);
    float ec1 = fast_exp2(c1);
    float ea0 = fast_exp2(a0);
    float eb0 = fast_exp2(b0);
    float ec0 = fast_exp2(c0);

    float sum1 = (ea1 + eb1) + ec1;
    float sum0 = (ea0 + eb0) + ec0;
    float rs1 = fast_rcp(sum1);
    float rs0 = fast_rcp(sum0);
    float l1  = fast_log2(sum1);
    float l0  = fast_log2(sum0);

    float df1 = t1 - o1, df0 = t0 - o0;
    float q1 = df1*df1,  q0 = df0*df0;
    float jv1 = __builtin_fmaf(ea1, dp2_0, __builtin_fmaf(eb1, dp1_0, ec1*dp1_1));
    float jv0 = __builtin_fmaf(ea0, dup2,  __builtin_fmaf(eb0, dup1,  ec0*dp1_0));
    float w1 = fd1*fd1, w0 = fd0*fd0;

    float c1v = __builtin_fmaf(-K2, q1, mn1 + l1);
    float c0v = __builtin_fmaf(-K2, q0, mn0 + l0);
    float d1v = __builtin_fmaf(rs1, jv1, w1);
    float d0v = __builtin_fmaf(rs0, jv0, w0);

    // rotate register pipelines
    p2_0 = p1_0;   p1_0 = c0v;  p1_1 = c1v;  up2 = up1;
    dp2_0 = dp1_0; dp1_0 = d0v; dp1_1 = d1v; dup2 = dup1;
    o1 = o0; o0 = o_nxt;
    fd0 -= 1.0f; fd1 -= 1.0f;
  }

  // lane 63 holds cell (128,128): R = -gamma*ln2 * R', Rdot = sum(E*Omega).
  if (lane == 63) {
    // 0.5*R/B + 0.5*Rdot/(B*T*T);  0.5*(gamma*ln2)/64 = 5.4152123e-5
    const float partial = __builtin_fmaf(p1_1, -5.415212348e-5f,
                                         dp1_1 * 4.76837158203125e-7f);
    atomicAdd(out, partial);
  }
}

extern "C" void kernel_launch(void* const* d_in, const int* in_sizes, int n_in,
                              void* d_out, int out_size, void* d_ws, size_t ws_size,
                              hipStream_t stream) {
  const float* outputs = (const float*)d_in[0];   // [64,128,4]
  const float* targets = (const float*)d_in[1];   // [64,128,4]
  float* out = (float*)d_out;                     // scalar fp32
  (void)in_sizes; (void)n_in; (void)out_size; (void)d_ws; (void)ws_size;

  // d_out is poisoned to 0xAA before every timed launch — zero it ourselves.
  (void)hipMemsetAsync(out, 0, sizeof(float), stream);
  // 256 blocks x 1 wave: all 256 CUs busy (R8: packing k seqs/SIMD loses).
  dilate_softdtw_kernel<<<dim3(256), dim3(64), 0, stream>>>(outputs, targets, out);
}

// Round 11
// 83.435 us; speedup vs baseline: 1.2423x; 1.0095x over previous
//
#include <hip/hip_runtime.h>

// DILATE loss: 0.5*soft-DTW(value) + 0.5*<softDTW-grad, Omega>.
// B=64, T=128, C=4 -> M=256 independent sequences, N=128, gamma=0.01.
//
// Fused forward pass carrying (R', Rdot): R' = -K2*R (log2-scaled), Rdot =
// JVP of soft-DTW value in direction Omega == sum(E*Omega). One block = one
// wave = one sequence (R8: packing k seqs per issue stream loses).
//
// R11 change: row-split. Instead of 254 steps x 2 cells/lane (~300 cyc/step,
// issue+gaps super-linear in per-step work), run TWO sequential 64-row halves
// with 1 cell/lane: 382 steps x ~half the per-step issue (5 trans + ~22 VALU).
// Lane l owns row r0+l. The row-64 boundary (R', Rdot) is passed via a
// 192-entry LDS float2 array: lane 63 writes Bb[d-1] in half 1; half 2
// injects Bb[d-2] as lane 0's DPP old-fill (up pred), register-rotated into
// the diag pred. Wall-sentinel padding handles all other boundaries (verified
// R6-R10: wall cells stay >= -1.3e7, exp args <= 0, weights flush to 0).

#define TN 128
#define BATCH 64
#define CH 4

__device__ __forceinline__ float fast_exp2(float x) { return __builtin_amdgcn_exp2f(x); }
__device__ __forceinline__ float fast_log2(float x) { return __builtin_amdgcn_logf(x); }
__device__ __forceinline__ float fast_rcp(float x)  { return __builtin_amdgcn_rcpf(x); }

// lane i <- lane i-1, lane 0 <- old(fill)   (DPP wave_shr:1) — HW-verified R4-R10
__device__ __forceinline__ float dpp_shr1(float x, float fill) {
  union { float f; int i; } o, s, r;
  o.f = fill; s.f = x;
  r.i = __builtin_amdgcn_update_dpp(o.i, s.i, 0x138, 0xF, 0xF, false);
  return r.f;
}

__global__ __launch_bounds__(64)
void dilate_softdtw_kernel(const float* __restrict__ outputs,
                           const float* __restrict__ targets,
                           float* __restrict__ out) {
  // padded o: oc[k]=o[k] for k in [0,128); pads hold O_PAD sentinel.
  __shared__ float obuf[384];
  // row-64 boundary: Bb[j+63] = {R'[64][j], Rdot[64][j]}. Written (half 1)
  // for indices 1..191; read (half 2) for indices 64..191 only.
  __shared__ float2 Bb[192];

  const float WALLP = -4.328085e6f;  // -K2*30000: boundary wall, scaled units
  const float O_PAD = 15.0f;         // sentinel: (t-15)^2 ~ 100..400 per OOB step
  const float K2    = 144.2695040888963f;     // (1/gamma)*log2(e)

  const int m = blockIdx.x, b = m >> 2, c = m & 3;
  const int lane = threadIdx.x;   // 0..63

  const float* tb = targets + (size_t)b*(TN*CH) + c;
  const float* ob = outputs + (size_t)b*(TN*CH) + c;

  #pragma unroll
  for (int s = 0; s < 6; ++s) {
    const int idx = lane + 64*s;
    const int k = idx - 126;
    obuf[idx] = ((unsigned)k <= 127u) ? ob[k*CH] : O_PAD;
  }
  const float tA = tb[lane*CH];          // t[i], i = 1+lane  (half 1)
  const float tB = tb[(64 + lane)*CH];   // t[i], i = 65+lane (half 2)
  __syncthreads();

  const float* oc = obuf + 126;

  float rRes = 0.f, dRes = 0.f;

  // ========== half 1: rows 1..64 (i = 1+lane), d = 2..192 ==========
  {
    const float t0 = tA;
    float p1  = WALLP;                          // R'[i][j-1] (left)
    float up2 = (lane == 0) ? 0.0f : WALLP;     // diag pred; lane0 d=2: R'[0][0]=0
    float dp1 = 0.f, dup2 = 0.f;                // Rdot counterparts
    float fd  = (float)(2*lane);                // i - j at d=2
    float o0  = oc[-lane];                      // o[j0-1] at d=2 (j0-1 = -lane)

    #pragma unroll 4
    for (int d = 2; d <= 192; ++d) {
      const int j0 = d - 1 - lane;              // j = d - i
      const float o_nxt = oc[j0];               // prefetch next iter's o[j0-1]
      float up1  = dpp_shr1(p1, WALLP);         // R'[i-1][j]   (row 0 -> wall)
      float dup1 = dpp_shr1(dp1, 0.f);          // Rdot[i-1][j]

      float mn = fmaxf(up2, fmaxf(up1, p1));
      float a = up2 - mn, bq = up1 - mn, cc = p1 - mn;
      float ea = fast_exp2(a);
      float eb = fast_exp2(bq);
      float ec = fast_exp2(cc);
      float sum = (ea + eb) + ec;
      float rs = fast_rcp(sum);
      float l  = fast_log2(sum);
      float df = t0 - o0;
      float q  = df*df;
      float jv = __builtin_fmaf(ea, dup2, __builtin_fmaf(eb, dup1, ec*dp1));
      float w  = fd*fd;
      float cv = __builtin_fmaf(-K2, q, mn + l);
      float dv = __builtin_fmaf(rs, jv, w);

      // lane 63 = row 64: publish boundary cell (64, j0), j0 = d-64 -> Bb[d-1].
      // Indices < 64 hold wall-like garbage; half 2 never reads them.
      if (lane == 63) Bb[d - 1] = make_float2(cv, dv);

      up2 = up1; p1 = cv; dup2 = dup1; dp1 = dv;
      o0 = o_nxt; fd -= 1.0f;
    }
  }
  __syncthreads();   // boundary writes -> half-2 reads (single wave: cheap)

  // ========== half 2: rows 65..128 (i = 65+lane), d = 66..256 ==========
  {
    const float t0 = tB;
    float p1  = WALLP, up2 = WALLP;    // up2 lane0 @d=66 stands in for R'[64][0] (wall)
    float dp1 = 0.f, dup2 = 0.f;
    float fd  = (float)(64 + 2*lane);  // i - j at d=66
    float o0  = oc[-lane];             // o[j0-1] at d=66 (j0-1 = -lane)
    float2 bc = Bb[64];                // boundary for d=66 (index d-2)

    #pragma unroll 4
    for (int d = 66; d <= 256; ++d) {
      const int j0 = d - 65 - lane;
      const float o_nxt = oc[j0];
      const int bi = (d - 1 > 191) ? 191 : (d - 1);   // clamp: j0>128 cells are garbage
      const float2 bn = Bb[bi];                       // prefetch next iter's boundary
      float up1  = dpp_shr1(p1, bc.x);   // lane 0 <- R'[64][j0]
      float dup1 = dpp_shr1(dp1, bc.y);  // lane 0 <- Rdot[64][j0]

      float mn = fmaxf(up2, fmaxf(up1, p1));
      float a = up2 - mn, bq = up1 - mn, cc = p1 - mn;
      float ea = fast_exp2(a);
      float eb = fast_exp2(bq);
      float ec = fast_exp2(cc);
      float sum = (ea + eb) + ec;
      float rs = fast_rcp(sum);
      float l  = fast_log2(sum);
      float df = t0 - o0;
      float q  = df*df;
      float jv = __builtin_fmaf(ea, dup2, __builtin_fmaf(eb, dup1, ec*dp1));
      float w  = fd*fd;
      float cv = __builtin_fmaf(-K2, q, mn + l);
      float dv = __builtin_fmaf(rs, jv, w);

      up2 = up1; p1 = cv; dup2 = dup1; dp1 = dv;
      o0 = o_nxt; fd -= 1.0f; bc = bn;
    }
    rRes = p1; dRes = dp1;   // lane 63: cell (128,128)
  }

  // lane 63: R = -gamma*ln2 * R', Rdot = sum(E*Omega).
  if (lane == 63) {
    // 0.5*R/B + 0.5*Rdot/(B*T*T);  0.5*(gamma*ln2)/64 = 5.4152123e-5
    const float partial = __builtin_fmaf(rRes, -5.415212348e-5f,
                                         dRes * 4.76837158203125e-7f);
    atomicAdd(out, partial);
  }
}

extern "C" void kernel_launch(void* const* d_in, const int* in_sizes, int n_in,
                              void* d_out, int out_size, void* d_ws, size_t ws_size,
                              hipStream_t stream) {
  const float* outputs = (const float*)d_in[0];   // [64,128,4]
  const float* targets = (const float*)d_in[1];   // [64,128,4]
  float* out = (float*)d_out;                     // scalar fp32
  (void)in_sizes; (void)n_in; (void)out_size; (void)d_ws; (void)ws_size;

  // d_out is poisoned to 0xAA before every timed launch — zero it ourselves.
  (void)hipMemsetAsync(out, 0, sizeof(float), stream);
  // 256 blocks x 1 wave: all 256 CUs busy (R8: packing k seqs/SIMD loses).
  dilate_softdtw_kernel<<<dim3(256), dim3(64), 0, stream>>>(outputs, targets, out);
}

// Round 12
// 82.810 us; speedup vs baseline: 1.2517x; 1.0075x over previous
//
#include <hip/hip_runtime.h>

// DILATE loss: 0.5*soft-DTW(value) + 0.5*<softDTW-grad, Omega>.
// B=64, T=128, C=4 -> M=256 independent sequences, N=128, gamma=0.01.
//
// Fused forward pass carrying (R', Rdot): R' = -K2*R (log2-scaled), Rdot =
// JVP of soft-DTW value in direction Omega == sum(E*Omega).
//
// R12: wavefront pipelining. R11 ran the two 64-row halves SEQUENTIALLY on
// one wave (382 steps x ~194 cyc). But the DAG's critical path is only 255
// diagonals: half 2's diagonal d needs only half 1's d-1. So: one block =
// 128 threads = 2 waves (different SIMDs), one sequence. Wave 0 = rows 1..64
// (d=2..192), wave 1 = rows 65..128 (d=66..256), running CONCURRENTLY with a
// ~K-step stagger. Boundary row 64 passes through LDS float2 Bb[] exactly as
// R11 (absmax 0.0 verified); producer-consumer sync via an LDS progress
// counter: wave 0 release-stores its completed d every K=8 steps (it NEVER
// waits -> no deadlock); wave 1 acquire-spins per 8-step chunk. Chunk
// targets (d0+7 = 73+8j) coincide exactly with publish points (1+8m).
// Per-cell math byte-identical to R11.

#define TN 128
#define BATCH 64
#define CH 4
#define KCH 8    // pipeline chunk (publish/wait granularity)

__device__ __forceinline__ float fast_exp2(float x) { return __builtin_amdgcn_exp2f(x); }
__device__ __forceinline__ float fast_log2(float x) { return __builtin_amdgcn_logf(x); }
__device__ __forceinline__ float fast_rcp(float x)  { return __builtin_amdgcn_rcpf(x); }

// lane i <- lane i-1, lane 0 <- old(fill)   (DPP wave_shr:1) — HW-verified R4-R11
__device__ __forceinline__ float dpp_shr1(float x, float fill) {
  union { float f; int i; } o, s, r;
  o.f = fill; s.f = x;
  r.i = __builtin_amdgcn_update_dpp(o.i, s.i, 0x138, 0xF, 0xF, false);
  return r.f;
}

__global__ __launch_bounds__(128)
void dilate_softdtw_kernel(const float* __restrict__ outputs,
                           const float* __restrict__ targets,
                           float* __restrict__ out) {
  // padded o: oc[k]=o[k] for k in [0,128); pads hold O_PAD sentinel.
  __shared__ float obuf[384];
  // row-64 boundary: Bb[d-1] = {R'[64][j], Rdot[64][j]} at j=d-64 (idx 1..191).
  __shared__ float2 Bb[192];
  __shared__ int prog;   // highest d wave 0 has completed (published every KCH)

  const float WALLP = -4.328085e6f;  // -K2*30000: boundary wall, scaled units
  const float O_PAD = 15.0f;         // sentinel: (t-15)^2 ~ 100..400 per OOB step
  const float K2    = 144.2695040888963f;     // (1/gamma)*log2(e)

  const int m = blockIdx.x, b = m >> 2, c = m & 3;
  const int tid  = threadIdx.x;
  const int wid  = tid >> 6;      // 0: rows 1..64, 1: rows 65..128
  const int lane = tid & 63;

  const float* tb = targets + (size_t)b*(TN*CH) + c;
  const float* ob = outputs + (size_t)b*(TN*CH) + c;

  #pragma unroll
  for (int s = 0; s < 3; ++s) {
    const int idx = tid + 128*s;
    const int k = idx - 126;
    obuf[idx] = ((unsigned)k <= 127u) ? ob[k*CH] : O_PAD;
  }
  const float t0 = tb[(wid*64 + lane)*CH];   // t[row], row = wid*64 + lane + 1
  if (tid == 0) prog = 0;
  __syncthreads();

  const float* oc = obuf + 126;

  if (wid == 0) {
    // ========== wave 0: rows 1..64 (i = 1+lane), d = 2..192 ==========
    float p1  = WALLP;                          // R'[i][j-1] (left)
    float up2 = (lane == 0) ? 0.0f : WALLP;     // diag pred; lane0 d=2: R'[0][0]=0
    float dp1 = 0.f, dup2 = 0.f;
    float fd  = (float)(2*lane);                // i - j at d=2
    float o0  = oc[-lane];                      // o[j0-1] at d=2

    #pragma unroll 4
    for (int d = 2; d <= 192; ++d) {
      const int j0 = d - 1 - lane;              // j = d - i
      const float o_nxt = oc[j0];
      float up1  = dpp_shr1(p1, WALLP);         // R'[i-1][j]   (row 0 -> wall)
      float dup1 = dpp_shr1(dp1, 0.f);          // Rdot[i-1][j]

      float mn = fmaxf(up2, fmaxf(up1, p1));
      float a = up2 - mn, bq = up1 - mn, cc = p1 - mn;
      float ea = fast_exp2(a);
      float eb = fast_exp2(bq);
      float ec = fast_exp2(cc);
      float sum = (ea + eb) + ec;
      float rs = fast_rcp(sum);
      float l  = fast_log2(sum);
      float df = t0 - o0;
      float q  = df*df;
      float jv = __builtin_fmaf(ea, dup2, __builtin_fmaf(eb, dup1, ec*dp1));
      float w  = fd*fd;
      float cv = __builtin_fmaf(-K2, q, mn + l);
      float dv = __builtin_fmaf(rs, jv, w);

      if (lane == 63) Bb[d - 1] = make_float2(cv, dv);   // boundary cell (64, d-64)
      if (((d - 1) & (KCH - 1)) == 0) {                  // publish d = 9,17,...,185
        if (lane == 63)
          __hip_atomic_store(&prog, d, __ATOMIC_RELEASE, __HIP_MEMORY_SCOPE_WORKGROUP);
      }

      up2 = up1; p1 = cv; dup2 = dup1; dp1 = dv;
      o0 = o_nxt; fd -= 1.0f;
    }
    if (lane == 63)
      __hip_atomic_store(&prog, 1000, __ATOMIC_RELEASE, __HIP_MEMORY_SCOPE_WORKGROUP);
  } else {
    // ========== wave 1: rows 65..128 (i = 65+lane), d = 66..256 ==========
    float p1  = WALLP, up2 = WALLP;    // lane0 @d=66 diag pred = R'[64][0] (wall)
    float dp1 = 0.f, dup2 = 0.f;
    float fd  = (float)(64 + 2*lane);  // i - j at d=66
    float o0  = oc[-lane];             // o[j0-1] at d=66
    float2 bc;                         // boundary Bb[d-2], rotated from prefetch
    bool first = true;

    for (int d0 = 66; d0 <= 256; d0 += KCH) {
      int target = d0 + KCH - 1;               // covers Bb up to d0+KCH-2 (incl. prefetch)
      if (target > 185) target = 1000;         // beyond last periodic publish
      while (__hip_atomic_load(&prog, __ATOMIC_ACQUIRE, __HIP_MEMORY_SCOPE_WORKGROUP) < target) {}
      if (first) { bc = Bb[64]; first = false; }   // Bb[d-2] for d=66

      const int dend = (d0 + KCH - 1 < 256) ? d0 + KCH - 1 : 256;
      #pragma unroll 4
      for (int d = d0; d <= dend; ++d) {
        const int j0 = d - 65 - lane;
        const float o_nxt = oc[j0];
        const int bi = (d - 1 > 191) ? 191 : (d - 1);   // clamp: j0>128 cells are garbage
        const float2 bn = Bb[bi];                       // prefetch next iter's boundary
        float up1  = dpp_shr1(p1, bc.x);   // lane 0 <- R'[64][j0]
        float dup1 = dpp_shr1(dp1, bc.y);  // lane 0 <- Rdot[64][j0]

        float mn = fmaxf(up2, fmaxf(up1, p1));
        float a = up2 - mn, bq = up1 - mn, cc = p1 - mn;
        float ea = fast_exp2(a);
        float eb = fast_exp2(bq);
        float ec = fast_exp2(cc);
        float sum = (ea + eb) + ec;
        float rs = fast_rcp(sum);
        float l  = fast_log2(sum);
        float df = t0 - o0;
        float q  = df*df;
        float jv = __builtin_fmaf(ea, dup2, __builtin_fmaf(eb, dup1, ec*dp1));
        float w  = fd*fd;
        float cv = __builtin_fmaf(-K2, q, mn + l);
        float dv = __builtin_fmaf(rs, jv, w);

        up2 = up1; p1 = cv; dup2 = dup1; dp1 = dv;
        o0 = o_nxt; fd -= 1.0f; bc = bn;
      }
    }

    // lane 63: cell (128,128). R = -gamma*ln2 * R', Rdot = sum(E*Omega).
    if (lane == 63) {
      // 0.5*R/B + 0.5*Rdot/(B*T*T);  0.5*(gamma*ln2)/64 = 5.4152123e-5
      const float partial = __builtin_fmaf(p1, -5.415212348e-5f,
                                           dp1 * 4.76837158203125e-7f);
      atomicAdd(out, partial);
    }
  }
}

extern "C" void kernel_launch(void* const* d_in, const int* in_sizes, int n_in,
                              void* d_out, int out_size, void* d_ws, size_t ws_size,
                              hipStream_t stream) {
  const float* outputs = (const float*)d_in[0];   // [64,128,4]
  const float* targets = (const float*)d_in[1];   // [64,128,4]
  float* out = (float*)d_out;                     // scalar fp32
  (void)in_sizes; (void)n_in; (void)out_size; (void)d_ws; (void)ws_size;

  // d_out is poisoned to 0xAA before every timed launch — zero it ourselves.
  (void)hipMemsetAsync(out, 0, sizeof(float), stream);
  // 256 blocks x 2 waves (one sequence each): waves pipeline the two row
  // halves on different SIMDs of one CU.
  dilate_softdtw_kernel<<<dim3(256), dim3(128), 0, stream>>>(outputs, targets, out);
}

// Round 13
// 76.374 us; speedup vs baseline: 1.3572x; 1.0843x over previous
//
#include <hip/hip_runtime.h>

// DILATE loss: 0.5*soft-DTW(value) + 0.5*<softDTW-grad, Omega>.
// B=64, T=128, C=4 -> M=256 independent sequences, N=128, gamma=0.01.
//
// Fused forward pass carrying (R', Rdot): R' = -K2*R (log2-scaled), Rdot =
// JVP of soft-DTW value in direction Omega == sum(E*Omega).
//
// R13: placement-robust 2-wave wavefront pipeline. R12 (128-thread block,
// waves 0/1 = halves of one sequence) conserved total cycles -> either both
// waves shared a SIMD (issue summed) or consumer overhead ate the win. Now:
// 256-thread block = 4 waves = TWO sequences; wave w -> (seq = w&1,
// half = w>>1). Round-robin placement: every wave gets its own SIMD.
// Fill-first placement: SIMD-sharing pairs are INDEPENDENT sequences (R8:
// independent waves fill each other's stalls to ~79% busy). Either way no
// producer/consumer pair shares an issue stream.
// Consumer trims vs R12: Bb[256] with prefilled wall tail (no clamp), no
// per-chunk 'first' branch, two-phase loop (gated chunks, then one final
// wait + branch-free 71-step tail).

#define TN 128
#define BATCH 64
#define CH 4
#define KCH 8    // pipeline chunk (publish/wait granularity)

__device__ __forceinline__ float fast_exp2(float x) { return __builtin_amdgcn_exp2f(x); }
__device__ __forceinline__ float fast_log2(float x) { return __builtin_amdgcn_logf(x); }
__device__ __forceinline__ float fast_rcp(float x)  { return __builtin_amdgcn_rcpf(x); }

// lane i <- lane i-1, lane 0 <- old(fill)   (DPP wave_shr:1) — HW-verified R4-R12
__device__ __forceinline__ float dpp_shr1(float x, float fill) {
  union { float f; int i; } o, s, r;
  o.f = fill; s.f = x;
  r.i = __builtin_amdgcn_update_dpp(o.i, s.i, 0x138, 0xF, 0xF, false);
  return r.f;
}

__global__ __launch_bounds__(256)
void dilate_softdtw_kernel(const float* __restrict__ outputs,
                           const float* __restrict__ targets,
                           float* __restrict__ out) {
  // per-sequence padded o: oc[k]=o[k] for k in [0,128); pads hold O_PAD.
  __shared__ float obuf[2][384];
  // per-sequence row-64 boundary: Bb[d-1] = {R'[64][j], Rdot[64][j]}, j=d-64.
  // Producer writes 1..191; 192..255 prefilled with wall (kills the clamp).
  __shared__ float2 Bb[2][256];
  __shared__ int prog[2];   // highest d the producer has completed

  const float WALLP = -4.328085e6f;  // -K2*30000: boundary wall, scaled units
  const float O_PAD = 15.0f;         // sentinel: (t-15)^2 ~ 100..400 per OOB step
  const float K2    = 144.2695040888963f;     // (1/gamma)*log2(e)

  const int tid  = threadIdx.x;
  const int wid  = tid >> 6;
  const int lane = tid & 63;
  const int seq  = wid & 1;       // which of the block's two sequences
  const int half = wid >> 1;      // 0: rows 1..64 (producer), 1: rows 65..128 (consumer)

  const int m = blockIdx.x * 2 + seq, b = m >> 2, c = m & 3;
  const float* tb = targets + (size_t)b*(TN*CH) + c;
  const float* ob = outputs + (size_t)b*(TN*CH) + c;

  // staging: the seq's two waves (128 threads) fill obuf[seq].
  const int lid = half*64 + lane;   // 0..127 within the pair
  #pragma unroll
  for (int s = 0; s < 3; ++s) {
    const int idx = lid + 128*s;
    const int k = idx - 126;
    obuf[seq][idx] = ((unsigned)k <= 127u) ? ob[k*CH] : O_PAD;
  }
  if (half == 1) Bb[seq][192 + lane] = make_float2(WALLP, 0.f);  // wall tail
  const float t0 = tb[(half*64 + lane)*CH];   // t[row], row = half*64+lane+1
  if (lid == 0) prog[seq] = 0;
  __syncthreads();

  const float* oc = obuf[seq] + 126;
  int* pp = &prog[seq];

  if (half == 0) {
    // ========== producer: rows 1..64 (i = 1+lane), d = 2..192 ==========
    float p1  = WALLP;                          // R'[i][j-1] (left)
    float up2 = (lane == 0) ? 0.0f : WALLP;     // diag pred; lane0 d=2: R'[0][0]=0
    float dp1 = 0.f, dup2 = 0.f;
    float fd  = (float)(2*lane);                // i - j at d=2
    float o0  = oc[-lane];                      // o[j0-1] at d=2

    #pragma unroll 4
    for (int d = 2; d <= 192; ++d) {
      const int j0 = d - 1 - lane;              // j = d - i
      const float o_nxt = oc[j0];
      float up1  = dpp_shr1(p1, WALLP);         // R'[i-1][j]   (row 0 -> wall)
      float dup1 = dpp_shr1(dp1, 0.f);          // Rdot[i-1][j]

      float mn = fmaxf(up2, fmaxf(up1, p1));
      float a = up2 - mn, bq = up1 - mn, cc = p1 - mn;
      float ea = fast_exp2(a);
      float eb = fast_exp2(bq);
      float ec = fast_exp2(cc);
      float sum = (ea + eb) + ec;
      float rs = fast_rcp(sum);
      float l  = fast_log2(sum);
      float df = t0 - o0;
      float q  = df*df;
      float jv = __builtin_fmaf(ea, dup2, __builtin_fmaf(eb, dup1, ec*dp1));
      float w  = fd*fd;
      float cv = __builtin_fmaf(-K2, q, mn + l);
      float dv = __builtin_fmaf(rs, jv, w);

      if (lane == 63) Bb[seq][d - 1] = make_float2(cv, dv);  // cell (64, d-64)
      if (((d - 1) & (KCH - 1)) == 0) {                      // d = 9,17,...,185
        if (lane == 63)
          __hip_atomic_store(pp, d, __ATOMIC_RELEASE, __HIP_MEMORY_SCOPE_WORKGROUP);
      }

      up2 = up1; p1 = cv; dup2 = dup1; dp1 = dv;
      o0 = o_nxt; fd -= 1.0f;
    }
    if (lane == 63)
      __hip_atomic_store(pp, 1000, __ATOMIC_RELEASE, __HIP_MEMORY_SCOPE_WORKGROUP);
  } else {
    // ========== consumer: rows 65..128 (i = 65+lane), d = 66..256 ==========
    float p1  = WALLP, up2 = WALLP;    // lane0 @d=66 diag pred = R'[64][0] (wall)
    float dp1 = 0.f, dup2 = 0.f;
    float fd  = (float)(64 + 2*lane);  // i - j at d=66
    float o0  = oc[-lane];             // o[j0-1] at d=66

    // one consumer macro-step
    auto cstep = [&](int d, float2& bc) {
      const int j0 = d - 65 - lane;
      const float o_nxt = oc[j0];
      const float2 bn = Bb[seq][d - 1];  // prefetch next iter's boundary (no clamp)
      float up1  = dpp_shr1(p1, bc.x);   // lane 0 <- R'[64][j0]
      float dup1 = dpp_shr1(dp1, bc.y);  // lane 0 <- Rdot[64][j0]

      float mn = fmaxf(up2, fmaxf(up1, p1));
      float a = up2 - mn, bq = up1 - mn, cc = p1 - mn;
      float ea = fast_exp2(a);
      float eb = fast_exp2(bq);
      float ec = fast_exp2(cc);
      float sum = (ea + eb) + ec;
      float rs = fast_rcp(sum);
      float l  = fast_log2(sum);
      float df = t0 - o0;
      float q  = df*df;
      float jv = __builtin_fmaf(ea, dup2, __builtin_fmaf(eb, dup1, ec*dp1));
      float w  = fd*fd;
      float cv = __builtin_fmaf(-K2, q, mn + l);
      float dv = __builtin_fmaf(rs, jv, w);

      up2 = up1; p1 = cv; dup2 = dup1; dp1 = dv;
      o0 = o_nxt; fd -= 1.0f; bc = bn;
    };

    // phase 1: gated chunks d0 = 66, 74, ..., 178 (targets 73..185, all published)
    while (__hip_atomic_load(pp, __ATOMIC_ACQUIRE, __HIP_MEMORY_SCOPE_WORKGROUP) < 73) {}
    float2 bc = Bb[seq][64];                    // boundary Bb[d-2] for d=66
    for (int d0 = 66; d0 <= 178; d0 += KCH) {
      const int target = d0 + KCH - 1;
      while (__hip_atomic_load(pp, __ATOMIC_ACQUIRE, __HIP_MEMORY_SCOPE_WORKGROUP) < target) {}
      #pragma unroll
      for (int k = 0; k < KCH; ++k) cstep(d0 + k, bc);
    }
    // phase 2: wait for producer completion, then branch-free tail d=186..256
    while (__hip_atomic_load(pp, __ATOMIC_ACQUIRE, __HIP_MEMORY_SCOPE_WORKGROUP) < 1000) {}
    #pragma unroll 4
    for (int d = 186; d <= 256; ++d) cstep(d, bc);

    // lane 63: cell (128,128). R = -gamma*ln2 * R', Rdot = sum(E*Omega).
    if (lane == 63) {
      // 0.5*R/B + 0.5*Rdot/(B*T*T);  0.5*(gamma*ln2)/64 = 5.4152123e-5
      const float partial = __builtin_fmaf(p1, -5.415212348e-5f,
                                           dp1 * 4.76837158203125e-7f);
      atomicAdd(out, partial);
    }
  }
}

extern "C" void kernel_launch(void* const* d_in, const int* in_sizes, int n_in,
                              void* d_out, int out_size, void* d_ws, size_t ws_size,
                              hipStream_t stream) {
  const float* outputs = (const float*)d_in[0];   // [64,128,4]
  const float* targets = (const float*)d_in[1];   // [64,128,4]
  float* out = (float*)d_out;                     // scalar fp32
  (void)in_sizes; (void)n_in; (void)out_size; (void)d_ws; (void)ws_size;

  // d_out is poisoned to 0xAA before every timed launch — zero it ourselves.
  (void)hipMemsetAsync(out, 0, sizeof(float), stream);
  // 128 blocks x 256 threads: 2 sequences/block, each a 2-wave pipeline.
  dilate_softdtw_kernel<<<dim3(128), dim3(256), 0, stream>>>(outputs, targets, out);
}